// Round 9
// baseline (272.308 us; speedup 1.0000x reference)
//
#include <hip/hip_runtime.h>
#include <math.h>

#define NB 16
#define NS 4096
#define DIN 512
#define NG 2
#define NC 320
#define GC 640          // NG*NC
#define DG 128          // D_out / G
#define NROW (NB*NS)    // 65536
#define NKT 16          // K tiles of 32
#define NCT 40          // col tiles of 16
#define EPSV 1e-10f

typedef __attribute__((ext_vector_type(4))) float f32x4;
typedef __attribute__((ext_vector_type(8))) _Float16 f16x8;

// async global->LDS (fallback path only)
__device__ __forceinline__ void gload_lds16(const void* g, void* l) {
    __builtin_amdgcn_global_load_lds(
        (const __attribute__((address_space(1))) void*)g,
        (__attribute__((address_space(3))) void*)l,
        16, 0, 0);
}

// ---------- W: split f32 -> (f16 hi, f16 lo*2048) packed in MFMA-frag order ----------
// dst[(kslice*40 + coltile)*64 + lane][8], lane = (col&15) + 16*kq, k = kslice*32+kq*8+j
__global__ __launch_bounds__(256) void cvt_split_pack(
    const float* __restrict__ W, _Float16* __restrict__ hp, _Float16* __restrict__ lp)
{
    int idx = blockIdx.x * 256 + threadIdx.x;   // one per (col, k8); 640*64
    if (idx >= GC * (DIN / 8)) return;
    int col = idx >> 6, k8 = idx & 63;
    int kslice = k8 >> 2, kq = k8 & 3, ntile = col >> 4;
    int ln = (col & 15) + 16 * kq;
    size_t dst = (((size_t)kslice * NCT + ntile) * 64 + ln) * 8;
    const float* src = W + (size_t)col * DIN + k8 * 8;
    f16x8 h, l;
    #pragma unroll
    for (int j = 0; j < 8; ++j) {
        float x = src[j];
        _Float16 hh = (_Float16)x;
        h[j] = hh;
        l[j] = (_Float16)((x - (float)hh) * 2048.0f);
    }
    *(f16x8*)(hp + dst) = h;
    *(f16x8*)(lp + dst) = l;
}

// ---------- MFMA GEMM v3: B-frags from L2 to regs, A reg-staged via LDS ----------
// logits = Ah*Bh + 2^-11*(Ah*Bl + Al*Bh) + b   (bitwise-identical to r8 sequence)
__global__ __launch_bounds__(512, 4) void mfma_logits3(
    const float* __restrict__ X,
    const _Float16* __restrict__ Whp, const _Float16* __restrict__ Wlp,
    const float* __restrict__ bias, float* __restrict__ logits)
{
    __shared__ _Float16 sA[2][2][128 * 32];   // 32 KB total

    const int t = threadIdx.x;                // 0..511
    const int lane = t & 63;
    const int w = t >> 6;
    const int wm = w >> 2, wn = w & 3;        // 2M x 4N; wave tile 64x32

    // XCD swizzle: 5 N-blocks of an M-panel share an XCD (2560 % 8 == 0)
    const int p = blockIdx.x;
    const int o = (p & 7) * 320 + (p >> 3);
    const int mb = o / 5, nb = o - mb * 5;
    const int row0 = mb * 128, n0 = nb * 128;
    const int ct0 = (n0 >> 4) + wn * 2;       // this wave's two B col-tiles

    // A reg-staging: thread owns (row = t>>2, k-slot q = t&3) of the 128x32 panel
    const int ar = t >> 2, aq = t & 3;
    const int aidx = ar * 32 + 8 * (aq ^ ((ar >> 1) & 3));  // XOR-swizzled LDS pos
    const float* aga = X + (size_t)(row0 + ar) * DIN + 8 * aq;

    float4 a0, a1;
    auto loadA = [&](int k0) {
        a0 = ((const float4*)(aga + k0))[0];
        a1 = ((const float4*)(aga + k0))[1];
    };
    auto writeA = [&](int b) {
        float xs[8] = {a0.x, a0.y, a0.z, a0.w, a1.x, a1.y, a1.z, a1.w};
        f16x8 h, l;
        #pragma unroll
        for (int j = 0; j < 8; ++j) {
            _Float16 hh = (_Float16)xs[j];
            h[j] = hh;
            l[j] = (_Float16)((xs[j] - (float)hh) * 2048.0f);
        }
        *(f16x8*)&sA[b][0][aidx] = h;
        *(f16x8*)&sA[b][1][aidx] = l;
    };

    f32x4 accA[4][2], accB[4][2];
    const f32x4 zz = {0.f, 0.f, 0.f, 0.f};
    #pragma unroll
    for (int mt = 0; mt < 4; ++mt)
        #pragma unroll
        for (int nt = 0; nt < 2; ++nt) { accA[mt][nt] = zz; accB[mt][nt] = zz; }

    loadA(0);
    writeA(0);
    asm volatile("s_waitcnt lgkmcnt(0)" ::: "memory");
    __builtin_amdgcn_s_barrier();
    __builtin_amdgcn_sched_barrier(0);

    for (int ks = 0; ks < NKT; ++ks) {
        const int cur = ks & 1;
        if (ks < NKT - 1) loadA((ks + 1) * 32);

        // B fragments straight from L2 (packed layout, 16B/lane coalesced);
        // counted vmcnt handled by the compiler — no barrier interaction.
        f16x8 bh[2], bl[2];
        #pragma unroll
        for (int nt = 0; nt < 2; ++nt) {
            size_t off = (((size_t)ks * NCT) + ct0 + nt) * 64 + lane;
            bh[nt] = *(const f16x8*)(Whp + off * 8);
            bl[nt] = *(const f16x8*)(Wlp + off * 8);
        }
        f16x8 ah[4], al[4];
        #pragma unroll
        for (int mt = 0; mt < 4; ++mt) {
            int r = wm * 64 + mt * 16 + (lane & 15);
            int idx = r * 32 + 8 * ((lane >> 4) ^ ((r >> 1) & 3));
            ah[mt] = *(const f16x8*)&sA[cur][0][idx];
            al[mt] = *(const f16x8*)&sA[cur][1][idx];
        }
        #pragma unroll
        for (int mt = 0; mt < 4; ++mt)
            #pragma unroll
            for (int nt = 0; nt < 2; ++nt) {
                accA[mt][nt] = __builtin_amdgcn_mfma_f32_16x16x32_f16(ah[mt], bh[nt], accA[mt][nt], 0, 0, 0);
                accB[mt][nt] = __builtin_amdgcn_mfma_f32_16x16x32_f16(ah[mt], bl[nt], accB[mt][nt], 0, 0, 0);
                accB[mt][nt] = __builtin_amdgcn_mfma_f32_16x16x32_f16(al[mt], bh[nt], accB[mt][nt], 0, 0, 0);
            }

        if (ks < NKT - 1) {
            writeA(cur ^ 1);                              // auto vmcnt for a-regs
            asm volatile("s_waitcnt lgkmcnt(0)" ::: "memory");  // publish ds_writes + drain my reads
            __builtin_amdgcn_s_barrier();
            __builtin_amdgcn_sched_barrier(0);
        }
    }

    // combine chains + bias, store f32 logits (identical to r8)
    #pragma unroll
    for (int nt = 0; nt < 2; ++nt) {
        int col = n0 + wn * 32 + nt * 16 + (lane & 15);
        float bv = bias[col];
        #pragma unroll
        for (int mt = 0; mt < 4; ++mt) {
            #pragma unroll
            for (int q = 0; q < 4; ++q) {
                int row = row0 + wm * 64 + mt * 16 + (lane >> 4) * 4 + q;
                logits[(size_t)row * GC + col] =
                    accA[mt][nt][q] + accB[mt][nt][q] * (1.0f / 2048.0f) + bv;
            }
        }
    }
}

// ---------- epilogue: ballot-argmax, unstabilized usage softmax (r7-proven) ----------
#define RTB 32
__global__ __launch_bounds__(256, 8) void epilogue(
    const float* __restrict__ logits, const int* __restrict__ vlen,
    const float* __restrict__ U, const float* __restrict__ CB,
    float* __restrict__ out, float* __restrict__ gacc)
{
    __shared__ float uacc[GC];
    const int t = threadIdx.x;
    const int lane = t & 63;
    const int wid = t >> 6;
    const int row0 = blockIdx.x * RTB;

    for (int i = t; i < GC; i += 256) uacc[i] = 0.0f;
    __syncthreads();

    const int vl = vlen[row0 >> 12];

    float ureg[10];
    #pragma unroll
    for (int j = 0; j < 10; ++j) ureg[j] = 0.0f;

    #pragma unroll
    for (int r = 0; r < 8; ++r) {
        const int row = row0 + wid * 8 + r;
        const bool valid = (row & (NS - 1)) < vl;

        float lg[10], zz[10];
        #pragma unroll
        for (int j = 0; j < 10; ++j)
            lg[j] = logits[(size_t)row * GC + lane + 64 * j];
        #pragma unroll
        for (int j = 0; j < 10; ++j) {
            float u = U[(size_t)row * GC + lane + 64 * j];
            zz[j] = lg[j] - logf(-logf(u + EPSV) + EPSV);   // precise: argmax-critical
        }

        #pragma unroll
        for (int g = 0; g < 2; ++g) {
            const int j0 = g * 5;

            float mv = zz[j0];
            #pragma unroll
            for (int j = j0 + 1; j < j0 + 5; ++j) mv = fmaxf(mv, zz[j]);
            #pragma unroll
            for (int d = 1; d < 64; d <<= 1) mv = fmaxf(mv, __shfl_xor(mv, d));

            int c = 0;
            #pragma unroll
            for (int jj = 4; jj >= 0; --jj) {
                unsigned long long b = __ballot(zz[j0 + jj] == mv);
                if (b) c = (__ffsll(b) - 1) + 64 * jj;
            }

            float pe[5], s2 = 0.0f;
            #pragma unroll
            for (int jj = 0; jj < 5; ++jj) {
                pe[jj] = __expf(lg[j0 + jj]);
                s2 += pe[jj];
            }
            #pragma unroll
            for (int d = 1; d < 64; d <<= 1) s2 += __shfl_xor(s2, d);
            if (valid) {
                const float inv = 1.0f / s2;
                #pragma unroll
                for (int jj = 0; jj < 5; ++jj) ureg[j0 + jj] += pe[jj] * inv;
            }

            const float2 cv = ((const float2*)(CB + ((size_t)g * NC + c) * DG))[lane];
            ((float2*)(out + (size_t)row * (NG * DG) + g * DG))[lane] = cv;
        }
    }

    #pragma unroll
    for (int j = 0; j < 10; ++j)
        atomicAdd(&uacc[lane + 64 * j], ureg[j]);

    __syncthreads();
    for (int i = t; i < GC; i += 256) atomicAdd(&gacc[i], uacc[i]);
}

__global__ void finalize_usage(const float* __restrict__ gacc,
                               const int* __restrict__ vlen,
                               float* __restrict__ usage_out)
{
    int total = 0;
    #pragma unroll
    for (int b = 0; b < NB; ++b) total += vlen[b];
    int o = threadIdx.x;
    if (o < GC) usage_out[o] = gacc[o] / (float)total;
}

// ---------- fallback path (round-4, f32 VALU, proven 928 us) ----------
#define RT 32
#define KC 8
#define NIT (DIN/KC)

__global__ void transpose_w(const float* __restrict__ W, float* __restrict__ Wt) {
    int idx = blockIdx.x * 256 + threadIdx.x;
    if (idx >= GC * DIN) return;
    int k = idx / GC, o = idx - k * GC;
    Wt[idx] = W[(size_t)o * DIN + k];
}

__global__ __launch_bounds__(256, 2) void fused_main(
    const float* __restrict__ X, const int* __restrict__ vlen,
    const float* __restrict__ U, const float* __restrict__ Wt,
    const float* __restrict__ bias, const float* __restrict__ CB,
    const float* __restrict__ tptr, float* __restrict__ out,
    float* __restrict__ gacc)
{
    __shared__ __align__(16) float WtC[2][KC][GC];
    __shared__ __align__(16) float AC[2][RT][KC];
    __shared__ float uacc[GC];

    const int t = threadIdx.x;
    const int lane = t & 63;
    const int wid = t >> 6;
    const int row0 = blockIdx.x * RT;

    for (int i = t; i < GC; i += 256) uacc[i] = 0.0f;

    float acc[8][10];
    #pragma unroll
    for (int r = 0; r < 8; ++r)
        #pragma unroll
        for (int j = 0; j < 10; ++j) acc[r][j] = 0.0f;

    auto stage = [&](int b, int k0) {
        const float* gw = Wt + (size_t)k0 * GC;
        #pragma unroll
        for (int i = 0; i < 5; ++i) {
            int base = (wid * 5 + i) * 256;
            gload_lds16(gw + base + 4 * lane, &WtC[b][0][0] + base);
        }
        if (wid == 0) {
            const float* gx = X + (size_t)(row0 + (lane >> 1)) * DIN + k0 + 4 * (lane & 1);
            gload_lds16(gx, &AC[b][0][0]);
        }
    };

    stage(0, 0);
    __syncthreads();

    int cur = 0;
    for (int it = 0; it < NIT; ++it) {
        if (it + 1 < NIT) stage(cur ^ 1, (it + 1) * KC);
        #pragma unroll
        for (int kk = 0; kk < KC; ++kk) {
            float w[10];
            #pragma unroll
            for (int j = 0; j < 10; ++j) w[j] = WtC[cur][kk][lane + 64 * j];
            #pragma unroll
            for (int r = 0; r < 8; ++r) {
                float a = AC[cur][wid * 8 + r][kk];
                #pragma unroll
                for (int j = 0; j < 10; ++j) acc[r][j] = fmaf(a, w[j], acc[r][j]);
            }
        }
        __syncthreads();
        cur ^= 1;
    }

    float bv[10];
    #pragma unroll
    for (int j = 0; j < 10; ++j) bv[j] = bias[lane + 64 * j];
    #pragma unroll
    for (int r = 0; r < 8; ++r)
        #pragma unroll
        for (int j = 0; j < 10; ++j) acc[r][j] += bv[j];

    const float T = *tptr;
    const int vl = vlen[row0 >> 12];

    #pragma unroll
    for (int r = 0; r < 8; ++r) {
        const int row = row0 + wid * 8 + r;
        const int ss = row & (NS - 1);
        const bool valid = ss < vl;

        float z[10];
        #pragma unroll
        for (int j = 0; j < 10; ++j) {
            float u = U[(size_t)row * GC + lane + 64 * j];
            float gn = -logf(-logf(u + EPSV) + EPSV);
            z[j] = (acc[r][j] + gn) / T;
        }

        #pragma unroll
        for (int g = 0; g < 2; ++g) {
            const int j0 = g * 5;
            float mv = z[j0];
            int mo = lane + 64 * j0;
            #pragma unroll
            for (int j = j0 + 1; j < j0 + 5; ++j) {
                if (z[j] > mv) { mv = z[j]; mo = lane + 64 * j; }
            }
            #pragma unroll
            for (int d = 1; d < 64; d <<= 1) {
                float ov = __shfl_xor(mv, d);
                int   oo = __shfl_xor(mo, d);
                if (ov > mv || (ov == mv && oo < mo)) { mv = ov; mo = oo; }
            }
            float se = 0.0f;
            #pragma unroll
            for (int j = j0; j < j0 + 5; ++j) se += expf(z[j] - mv);
            #pragma unroll
            for (int d = 1; d < 64; d <<= 1) se += __shfl_xor(se, d);
            float y = 1.0f / se;
            float q = (1.0f - y) + y;

            float m2 = acc[r][j0];
            #pragma unroll
            for (int j = j0 + 1; j < j0 + 5; ++j) m2 = fmaxf(m2, acc[r][j]);
            #pragma unroll
            for (int d = 1; d < 64; d <<= 1) m2 = fmaxf(m2, __shfl_xor(m2, d));
            float pe[5];
            float s2 = 0.0f;
            #pragma unroll
            for (int jj = 0; jj < 5; ++jj) {
                pe[jj] = expf(acc[r][j0 + jj] - m2);
                s2 += pe[jj];
            }
            #pragma unroll
            for (int d = 1; d < 64; d <<= 1) s2 += __shfl_xor(s2, d);
            if (valid) {
                #pragma unroll
                for (int jj = 0; jj < 5; ++jj)
                    atomicAdd(&uacc[lane + 64 * (j0 + jj)], pe[jj] / s2);
            }

            const int c = mo - g * NC;
            const float2 cv = ((const float2*)(CB + ((size_t)g * NC + c) * DG))[lane];
            float2 ov2;
            ov2.x = q * cv.x;
            ov2.y = q * cv.y;
            ((float2*)(out + (size_t)row * (NG * DG) + g * DG))[lane] = ov2;
        }
    }

    __syncthreads();
    for (int i = t; i < GC; i += 256) atomicAdd(&gacc[i], uacc[i]);
}

extern "C" void kernel_launch(void* const* d_in, const int* in_sizes, int n_in,
                              void* d_out, int out_size, void* d_ws, size_t ws_size,
                              hipStream_t stream)
{
    const float* X    = (const float*)d_in[0];
    const int*   vlen = (const int*)d_in[1];
    const float* U    = (const float*)d_in[2];
    const float* W    = (const float*)d_in[3];
    const float* bias = (const float*)d_in[4];
    const float* CB   = (const float*)d_in[5];
    const float* T    = (const float*)d_in[6];
    float* out = (float*)d_out;

    char* ws = (char*)d_ws;
    float*     gacc = (float*)ws;                               // 2,560
    _Float16*  Whp  = (_Float16*)(ws + 4096);                   // 655,360
    _Float16*  Wlp  = (_Float16*)(ws + 659456);                 // 655,360
    float*     lgts = (float*)(ws + 1314816);                   // 167,772,160
    float*     Wt   = (float*)(ws + 4096);                      // fallback only
    const size_t need = 1314816ull + 167772160ull;              // ~169 MB

    hipMemsetAsync(gacc, 0, GC * sizeof(float), stream);

    if (ws_size >= need) {
        cvt_split_pack<<<(GC * (DIN / 8) + 255) / 256, 256, 0, stream>>>(W, Whp, Wlp);
        mfma_logits3<<<(NROW / 128) * 5, 512, 0, stream>>>(X, Whp, Wlp, bias, lgts);
        epilogue<<<NROW / RTB, 256, 0, stream>>>(lgts, vlen, U, CB, out, gacc);
    } else {
        transpose_w<<<(GC * DIN + 255) / 256, 256, 0, stream>>>(W, Wt);
        fused_main<<<NROW / RT, 256, 0, stream>>>(X, vlen, U, Wt, bias, CB, T, out, gacc);
    }
    finalize_usage<<<1, GC, 0, stream>>>(gacc, vlen, out + (size_t)NROW * (NG * DG));
}